// Round 7
// baseline (157.987 us; speedup 1.0000x reference)
//
#include <hip/hip_runtime.h>
#include <math.h>

#define N_T 2000
#define NG  500               // float4 groups per trial
#define TRIALS_PER_BLOCK 2    // 4 waves/block, 2 waves per trial

typedef float vf4 __attribute__((ext_vector_type(4)));

// Two waves per trial (halves the per-wave serial chain, doubles wave count
// for phase staggering). Strided layout: lane i of half h owns float4 group
// h*256 + j*64 + i  -> every global access 1KB-contiguous per wave64 instr.
// Closed form: e[t] = DEC^t * (sp + S[t]), S[t] = sum_{k<t} u[k]*INV^(k+1)
// (global scaling), so the cross-wave carry is a single float add passed
// through LDS. Nontemporal loads/stores throughout (R6 win).
__global__ __launch_bounds__(256, 5) void ddm_kernel(
    const float* __restrict__ stim,
    const float* __restrict__ noise,
    const float* __restrict__ a_p,
    const float* __restrict__ z_p,
    const float* __restrict__ gain_p,
    const float* __restrict__ off_p,
    const float* __restrict__ beta_p,
    float* __restrict__ out,
    int n_trials)
{
    __shared__ float half_tot[TRIALS_PER_BLOCK];

    const int wid  = threadIdx.x >> 6;   // 0..3
    const int lane = threadIdx.x & 63;
    const int tloc = wid >> 1;           // trial within block
    const int half = wid & 1;            // 0: t<1024, 1: t>=1024
    int trial = blockIdx.x * TRIALS_PER_BLOCK + tloc;
    if (trial >= n_trials) trial = n_trials - 1;   // keep sync uniform

    constexpr float DT   = 0.001f;
    constexpr float LEAK = 0.01f;
    constexpr float DEC  = 1.0f - LEAK * DT;       // 0.99999
    constexpr float INV  = 1.0f / DEC;
    constexpr float De2 = DEC * DEC, De3 = De2 * DEC, De4 = De2 * De2;
    constexpr float I2  = INV * INV, I3  = I2 * INV, I4  = I2 * I2;
    constexpr float D8 = De4 * De4, D16 = D8 * D8, D32 = D16 * D16,
                    D64 = D32 * D32, D128 = D64 * D64, D256 = D128 * D128;
    constexpr float I8 = I4 * I4, I16 = I8 * I8, I32 = I16 * I16,
                    I64 = I32 * I32, I128 = I64 * I64, I256 = I128 * I128;
    constexpr float D1024 = D256 * D256 * D256 * D256;
    constexpr float I1024 = I256 * I256 * I256 * I256;

    const float a    = *a_p;
    const float z    = *z_p;
    const float gain = *gain_p;
    const float offs = *off_p;
    const float beta = *beta_p;

    const float sp = z * a;
    const float C1 = gain * DT;
    const float C2 = sqrtf(1.0f * DT);             // sqrt(VARIANCE*DT)
    const float C3 = offs * DT + LEAK * sp * DT;

    // lane powers: dl = DEC^(4*lane), il = INV^(4*lane+1); then half offset
    float dl = 1.f, il = 1.f, bd = De4, bi = I4;
    int nb = lane;
#pragma unroll
    for (int b = 0; b < 6; ++b) {
        if (nb & 1) { dl *= bd; il *= bi; }
        bd *= bd; bi *= bi; nb >>= 1;
    }
    il *= INV;
    const float dlh = half ? dl * D1024 : dl;      // DEC^(4*g) lane base
    const float ilh = half ? il * I1024 : il;      // INV^(4*g+1) lane base

    const float* srow = stim  + (size_t)trial * N_T;
    const float* nrow = noise + (size_t)trial * N_T;
    const int gbase = half * 256;

    // ---- (1) this wave's 8 loads up front, nontemporal; clamp OOB ----
    vf4 sv[4], nv[4];
#pragma unroll
    for (int j = 0; j < 4; ++j) {
        const int g  = gbase + j * 64 + lane;
        const int gc = (g < NG) ? g : (NG - 1);
        sv[j] = __builtin_nontemporal_load((const vf4*)(srow + 4 * gc));
        nv[j] = __builtin_nontemporal_load((const vf4*)(nrow + 4 * gc));
    }

    // ---- (2) per-j lane prefix quads (globally scaled w) ----
    float l0[4], l1[4], l2[4], l3[4];
    {
        float ifj = ilh;
#pragma unroll
        for (int j = 0; j < 4; ++j) {
            const float m = ((gbase + j * 64 + lane) < NG) ? 1.f : 0.f;
            const float u0 = C1 * sv[j].x + C2 * nv[j].x + C3;
            const float u1 = C1 * sv[j].y + C2 * nv[j].y + C3;
            const float u2 = C1 * sv[j].z + C2 * nv[j].z + C3;
            const float u3 = C1 * sv[j].w + C2 * nv[j].w + C3;
            const float w0 = u0 * ifj * m;
            const float w1 = u1 * (ifj * INV) * m;
            const float w2 = u2 * (ifj * I2) * m;
            const float w3 = u3 * (ifj * I3) * m;
            l0[j] = w0;
            l1[j] = l0[j] + w1;
            l2[j] = l1[j] + w2;
            l3[j] = l2[j] + w3;
            ifj *= I256;
        }
    }

    // ---- (3) 4 independent wave scans, step-synchronous ----
    float sc[4];
#pragma unroll
    for (int j = 0; j < 4; ++j) sc[j] = l3[j];
#pragma unroll
    for (int off = 1; off < 64; off <<= 1) {
        float v[4];
#pragma unroll
        for (int j = 0; j < 4; ++j) v[j] = __shfl_up(sc[j], off, 64);
#pragma unroll
        for (int j = 0; j < 4; ++j) sc[j] += (lane >= off) ? v[j] : 0.f;
    }

    // ---- (4) carry composition within wave ----
    float S0[4];
    float c = 0.f;
#pragma unroll
    for (int j = 0; j < 4; ++j) {
        const float btot = __shfl(sc[j], 63, 64);
        S0[j] = c + (sc[j] - l3[j]);
        c += btot;
    }

    // ---- cross-wave carry: half 0 publishes its total ----
    if (!half && lane == 0) half_tot[tloc] = c;
    __syncthreads();
    const float cin = half ? half_tot[tloc] : 0.f;

    // ---- (5) outputs, nontemporal ----
    float* dv_out = out;
    float* h1_out = out + (size_t)n_trials * N_T;
    float* h0_out = out + 2 * (size_t)n_trials * N_T;
    const size_t rbase = (size_t)trial * N_T;
    const float spc = sp;   // alias

    float dpj = dlh;
#pragma unroll
    for (int j = 0; j < 4; ++j) {
        const int  g     = gbase + j * 64 + lane;
        const bool valid = g < NG;
        const int  t0    = 4 * g;
        const float Sb   = spc + cin + S0[j];

        const float e0 = dpj *         (Sb);
        const float e1 = (dpj * DEC) * (Sb + l0[j]);
        const float e2 = (dpj * De2) * (Sb + l1[j]);
        const float e3 = (dpj * De3) * (Sb + l2[j]);

        vf4 dv4, h14, h04;
        dv4.x = (float)(t0    ) * 0.01f * (e0 - spc) + spc;
        dv4.y = (float)(t0 + 1) * 0.01f * (e1 - spc) + spc;
        dv4.z = (float)(t0 + 2) * 0.01f * (e2 - spc) + spc;
        dv4.w = (float)(t0 + 3) * 0.01f * (e3 - spc) + spc;
#pragma unroll
        for (int q = 0; q < 4; ++q) {
            const float dv = dv4[q];
            h14[q] = __builtin_amdgcn_rcpf(1.0f + __expf(-beta * (dv - a)));
            h04[q] = __builtin_amdgcn_rcpf(1.0f + __expf( beta * dv));
        }

        if (valid) {
            const size_t base = rbase + (size_t)t0;
            __builtin_nontemporal_store(dv4, (vf4*)(dv_out + base));
            __builtin_nontemporal_store(h14, (vf4*)(h1_out + base));
            __builtin_nontemporal_store(h04, (vf4*)(h0_out + base));
        }
        dpj *= D256;
    }
}

extern "C" void kernel_launch(void* const* d_in, const int* in_sizes, int n_in,
                              void* d_out, int out_size, void* d_ws, size_t ws_size,
                              hipStream_t stream) {
    const float* stim  = (const float*)d_in[0];
    const float* noise = (const float*)d_in[1];
    const float* a_p   = (const float*)d_in[2];
    const float* z_p   = (const float*)d_in[3];
    const float* g_p   = (const float*)d_in[4];
    const float* o_p   = (const float*)d_in[5];
    const float* b_p   = (const float*)d_in[6];
    float* outp = (float*)d_out;

    const int n_trials = in_sizes[0] / N_T;
    const int blocks = (n_trials + TRIALS_PER_BLOCK - 1) / TRIALS_PER_BLOCK;
    ddm_kernel<<<blocks, 256, 0, stream>>>(stim, noise, a_p, z_p, g_p, o_p, b_p,
                                           outp, n_trials);
}